// Round 1
// 268.692 us; speedup vs baseline: 1.0045x; 1.0045x over previous
//
#include <hip/hip_runtime.h>
#include <hip/hip_bf16.h>

// B=8, S=4096, E=512, QKV=512, H=8, D=64, M=B*S=32768
// R6 pipeline (5 launches):
//   prep:      x fp32 -> bf16 (d_out hi half) + W transposes -> wt (ws)
//   gemm_qkv:  256x256 8-phase schedule (T3+T4+T5): q = act(x@Wq+b) row-major,
//              k,v stored ONLY TRANSPOSED kT/vT[bh][d][4096] bf16 (k act'd).
//              512 thr, 128KB LDS dbuf, counted vmcnt(4), setprio around MFMA.
//   kv:        MFMA GEMM over s: kv_part[m][d] = sum_s vT[m][s]*kT[d][s],
//              + ksum partials from staged kT tiles (16 s-chunks)
//   mid:       reduce ksum; z[h][row]=1/(q_h.ksum_h+eps); reduce kv -> bf16
//   fused_out: per 128x128 out block: loop h { o1_h = z*(q_h@kv_h^T) in LDS,
//              accumulate o1_h @ Wo_h } + bias -> d_out fp32 (XCD-swizzled)
// Scratch:
//   d_out[0,32M):  vT (dead after kv), then final out rows
//   d_out[32,64M): xb (dead after gemm_qkv) -> kvp partials -> final out rows
//   ws: qb[0,32M) kT[32,64M) wt[64,66M) ksp/kvb/zb[66,~71M)

typedef __bf16 bf16x8 __attribute__((ext_vector_type(8)));
typedef float  f32x4  __attribute__((ext_vector_type(4)));

__device__ __forceinline__ float b2f(unsigned short u) {
    unsigned int x = ((unsigned int)u) << 16;
    return __builtin_bit_cast(float, x);
}
__device__ __forceinline__ unsigned short f2b(float f) {
    unsigned int u = __builtin_bit_cast(unsigned int, f);
    unsigned int r = (u + 0x7FFFu + ((u >> 16) & 1u)) >> 16;
    return (unsigned short)r;
}
__device__ __forceinline__ void load_lds16(const unsigned short* g, unsigned short* l) {
    __builtin_amdgcn_global_load_lds(
        (const __attribute__((address_space(1))) void*)g,
        (__attribute__((address_space(3))) void*)l, 16, 0, 0);
}

// ---------------- prep: W transpose (blocks 0..255) + x cvt (blocks 256..) ---
__global__ void prep_kernel(const float* __restrict__ x,
                            const float* __restrict__ w0, const float* __restrict__ w1,
                            const float* __restrict__ w2, const float* __restrict__ w3,
                            unsigned short* __restrict__ xb, unsigned short* __restrict__ wt) {
    __shared__ float tile[64][65];
    int t = threadIdx.x;
    if (blockIdx.x >= 256) {
        int i = (blockIdx.x - 256) * 256 + t;   // < 4194304
        float4 v = ((const float4*)x)[i];
        ushort4 o;
        o.x = f2b(v.x); o.y = f2b(v.y); o.z = f2b(v.z); o.w = f2b(v.w);
        ((ushort4*)xb)[i] = o;
        return;
    }
    int idx = blockIdx.x;
    int bz = idx >> 6, by = (idx >> 3) & 7, bx = idx & 7;
    const float* src = (bz == 0) ? w0 : (bz == 1) ? w1 : (bz == 2) ? w2 : w3;
    unsigned short* dst = wt + (size_t)bz * 512 * 512;
    int rb = by * 64, cb = bx * 64;
    #pragma unroll
    for (int i = 0; i < 16; i++) {
        int c = t + i * 256; int r = c >> 6, cc = c & 63;
        tile[r][cc] = src[(rb + r) * 512 + cb + cc];
    }
    __syncthreads();
    #pragma unroll
    for (int i = 0; i < 16; i++) {
        int c = t + i * 256; int r = c >> 6, cc = c & 63;
        dst[(cb + r) * 512 + rb + cc] = f2b(tile[cc][r]);   // Wt[n][k]=W[k][n]
    }
}

// ---------------- gemm_qkv: 256x256 8-phase MFMA ----------------------------
// grid: 768 1-D, XCD-swizzled: all 6 (tensor,ntile) blocks of one mtile get
// equal blockIdx%8 -> same XCD -> A-tile L2 hit.
// 512 thr = 8 waves (2 wm x 4 wn), per-wave output 128x64 (acc[8][4] 16x16).
// LDS: 2 bufs x (A 256x64 + B 256x64) bf16 = 128 KiB.
// Schedule per K-tile t (4 phases), reading buf[t&1]:
//   P1: ds_read af(i0..3)x2 + bf(j0..3)x2 (16); stage A-half0(t+1); MFMA 16; bar
//   P2: stage A-half1(t+1); MFMA 16; lgkmcnt(0); bar   <- all buf reads landed
//   P3: ds_read a2(i4..7)x2 (8); stage B-half0(t+2) [into buf[t&1], safe]; MFMA 16; bar
//   P4: stage B-half1(t+2); MFMA 16; vmcnt(4); bar     <- tile t+1 fully staged
// vmcnt is never 0 in the loop (T4). Tail stages clamp the source K index and
// land in dead buffer regions (race-free: A-halves target the other buffer,
// B-halves target the current buffer only after the P2 read-complete barrier).
__global__ __launch_bounds__(512, 1) void gemm_qkv_kernel(
        const unsigned short* __restrict__ xb, const unsigned short* __restrict__ wt,
        const float* __restrict__ bq, const float* __restrict__ bk, const float* __restrict__ bv,
        unsigned short* __restrict__ qb, unsigned short* __restrict__ kT,
        unsigned short* __restrict__ vT) {
    __shared__ __align__(16) unsigned short lds[65536];   // 128 KiB
    int g = blockIdx.x;
    int xcd = g & 7, slot = g >> 3;            // slot 0..95
    int mtile = xcd * 16 + slot / 6;
    int tn = slot % 6;
    int tensor = tn >> 1, ntile = tn & 1;
    const unsigned short* Bt = wt + (size_t)tensor * 512 * 512;
    const float* bias = tensor == 0 ? bq : tensor == 1 ? bk : bv;
    bool act = tensor < 2;

    const int tid  = threadIdx.x;
    const int wave = tid >> 6, lane = tid & 63;
    const int wm = wave >> 2, wn = wave & 3;
    const int quad = lane >> 4, l16 = lane & 15;
    const int rsub = lane >> 3;
    const int coff = (((lane & 7) ^ rsub) << 3);
    const int mbase = mtile * 256, nbase = ntile * 256;
    const int pg0 = ((quad)     ^ (l16 & 7)) << 3;
    const int pg1 = ((quad + 4) ^ (l16 & 7)) << 3;

    // stage one 128-row half-tile (2 global_load_lds per thread)
    auto stageA = [&](int ts, int h) {
        int tc = ts < 7 ? ts : 7;
        unsigned short* dst = &lds[(ts & 1) * 32768 + h * 8192];
        int rb = mbase + h * 128, kb = tc * 64;
        #pragma unroll
        for (int rnd = 0; rnd < 2; rnd++) {
            int r0 = rnd * 64 + wave * 8;
            load_lds16(&xb[(size_t)(rb + r0 + rsub) * 512 + kb + coff], &dst[r0 * 64]);
        }
    };
    auto stageB = [&](int ts, int h) {
        int tc = ts < 7 ? ts : 7;
        unsigned short* dst = &lds[(ts & 1) * 32768 + 16384 + h * 8192];
        int rb = nbase + h * 128, kb = tc * 64;
        #pragma unroll
        for (int rnd = 0; rnd < 2; rnd++) {
            int r0 = rnd * 64 + wave * 8;
            load_lds16(&Bt[(size_t)(rb + r0 + rsub) * 512 + kb + coff], &dst[r0 * 64]);
        }
    };

    f32x4 acc[8][4];
    #pragma unroll
    for (int i = 0; i < 8; i++)
        #pragma unroll
        for (int j = 0; j < 4; j++) acc[i][j] = (f32x4){0.f, 0.f, 0.f, 0.f};

    // prologue: tile0 A+B, tile1 B (A of tile1 staged during tile0 P1/P2)
    stageA(0, 0); stageA(0, 1);
    stageB(0, 0); stageB(0, 1);
    stageB(1, 0); stageB(1, 1);
    asm volatile("s_waitcnt vmcnt(4)" ::: "memory");   // tile0 staged; tile1 B in flight
    __builtin_amdgcn_s_barrier();

    #pragma unroll 2
    for (int t = 0; t < 8; ++t) {
        const unsigned short* A = &lds[(t & 1) * 32768];
        const unsigned short* Bl = &lds[(t & 1) * 32768 + 16384];
        // ---- P1 ----
        bf16x8 af[4][2], bf[4][2];
        #pragma unroll
        for (int i = 0; i < 4; i++) {
            af[i][0] = *(const bf16x8*)&A[(wm * 128 + i * 16 + l16) * 64 + pg0];
            af[i][1] = *(const bf16x8*)&A[(wm * 128 + i * 16 + l16) * 64 + pg1];
        }
        #pragma unroll
        for (int j = 0; j < 4; j++) {
            bf[j][0] = *(const bf16x8*)&Bl[(wn * 64 + j * 16 + l16) * 64 + pg0];
            bf[j][1] = *(const bf16x8*)&Bl[(wn * 64 + j * 16 + l16) * 64 + pg1];
        }
        stageA(t + 1, 0);
        __builtin_amdgcn_s_setprio(1);
        #pragma unroll
        for (int i = 0; i < 4; i++)
            #pragma unroll
            for (int j = 0; j < 2; j++) {
                acc[i][j] = __builtin_amdgcn_mfma_f32_16x16x32_bf16(af[i][0], bf[j][0], acc[i][j], 0, 0, 0);
                acc[i][j] = __builtin_amdgcn_mfma_f32_16x16x32_bf16(af[i][1], bf[j][1], acc[i][j], 0, 0, 0);
            }
        __builtin_amdgcn_s_setprio(0);
        __builtin_amdgcn_s_barrier();
        // ---- P2 ----
        stageA(t + 1, 1);
        __builtin_amdgcn_s_setprio(1);
        #pragma unroll
        for (int i = 0; i < 4; i++)
            #pragma unroll
            for (int j = 2; j < 4; j++) {
                acc[i][j] = __builtin_amdgcn_mfma_f32_16x16x32_bf16(af[i][0], bf[j][0], acc[i][j], 0, 0, 0);
                acc[i][j] = __builtin_amdgcn_mfma_f32_16x16x32_bf16(af[i][1], bf[j][1], acc[i][j], 0, 0, 0);
            }
        __builtin_amdgcn_s_setprio(0);
        asm volatile("s_waitcnt lgkmcnt(0)" ::: "memory");  // all buf[t&1] reads landed
        __builtin_amdgcn_sched_barrier(0);
        __builtin_amdgcn_s_barrier();
        // ---- P3 ----
        bf16x8 a2[4][2];
        #pragma unroll
        for (int i = 0; i < 4; i++) {
            a2[i][0] = *(const bf16x8*)&A[(wm * 128 + (i + 4) * 16 + l16) * 64 + pg0];
            a2[i][1] = *(const bf16x8*)&A[(wm * 128 + (i + 4) * 16 + l16) * 64 + pg1];
        }
        stageB(t + 2, 0);
        __builtin_amdgcn_s_setprio(1);
        #pragma unroll
        for (int i = 0; i < 4; i++)
            #pragma unroll
            for (int j = 0; j < 2; j++) {
                acc[i + 4][j] = __builtin_amdgcn_mfma_f32_16x16x32_bf16(a2[i][0], bf[j][0], acc[i + 4][j], 0, 0, 0);
                acc[i + 4][j] = __builtin_amdgcn_mfma_f32_16x16x32_bf16(a2[i][1], bf[j][1], acc[i + 4][j], 0, 0, 0);
            }
        __builtin_amdgcn_s_setprio(0);
        __builtin_amdgcn_s_barrier();
        // ---- P4 ----
        stageB(t + 2, 1);
        __builtin_amdgcn_s_setprio(1);
        #pragma unroll
        for (int i = 0; i < 4; i++)
            #pragma unroll
            for (int j = 2; j < 4; j++) {
                acc[i + 4][j] = __builtin_amdgcn_mfma_f32_16x16x32_bf16(a2[i][0], bf[j][0], acc[i + 4][j], 0, 0, 0);
                acc[i + 4][j] = __builtin_amdgcn_mfma_f32_16x16x32_bf16(a2[i][1], bf[j][1], acc[i + 4][j], 0, 0, 0);
            }
        __builtin_amdgcn_s_setprio(0);
        asm volatile("s_waitcnt vmcnt(4)" ::: "memory");    // tile t+1 fully staged
        __builtin_amdgcn_s_barrier();
    }

    // epilogue. C/D layout: col = lane&15, row = quad*4+reg (m89-verified).
    if (tensor == 0) {
        #pragma unroll
        for (int i = 0; i < 8; i++)
            #pragma unroll
            for (int j = 0; j < 4; j++) {
                int gcol = nbase + wn * 64 + j * 16 + l16;
                float bv = bias[gcol];
                #pragma unroll
                for (int r = 0; r < 4; r++) {
                    int grow = mbase + wm * 128 + i * 16 + quad * 4 + r;
                    float v = acc[i][j][r] + bv;
                    v = v > 0.f ? v + 1.f : __expf(v);
                    qb[(size_t)grow * 512 + gcol] = f2b(v);
                }
            }
    } else {
        // transposed store: T[((b*8+h)*64 + d)*4096 + s], 4 consecutive s
        // (the 4 acc regs = rows quad*4+0..3) packed into one ushort4.
        unsigned short* T = (tensor == 1) ? kT : vT;
        #pragma unroll
        for (int i = 0; i < 8; i++)
            #pragma unroll
            for (int j = 0; j < 4; j++) {
                int gcol = nbase + wn * 64 + j * 16 + l16;   // 0..511
                int h = gcol >> 6, d = gcol & 63;
                float bv = bias[gcol];
                int grow0 = mbase + wm * 128 + i * 16 + quad * 4;
                int b = grow0 >> 12, s0 = grow0 & 4095;
                ushort4 o;
                #pragma unroll
                for (int r = 0; r < 4; r++) {
                    float v = acc[i][j][r] + bv;
                    if (act) v = v > 0.f ? v + 1.f : __expf(v);
                    ((unsigned short*)&o)[r] = f2b(v);
                }
                *(ushort4*)&T[(((size_t)b * 8 + h) * 64 + d) * 4096 + s0] = o;
            }
    }
}

// ---------------- kv: MFMA GEMM over s + ksum --------------------------------
// grid: x = bh(64) * sc(16); block: C[64 m][64 d] partial over 256 s.
// A = vT rows (m), B = kT rows (d), both K-major -> m97 staging applies.
__global__ __launch_bounds__(256, 4) void kv_kernel(
        const unsigned short* __restrict__ kT, const unsigned short* __restrict__ vT,
        float* __restrict__ kvp, float* __restrict__ ksp) {
    int bh = blockIdx.x >> 4, sc = blockIdx.x & 15;
    const int tid = threadIdx.x;
    const int wave = tid >> 6, lane = tid & 63;
    const int wm = wave >> 1, wn = wave & 1;
    const int quad = lane >> 4, l16 = lane & 15;
    const int rsub = lane >> 3;
    const int coff = (((lane & 7) ^ rsub) << 3);
    __shared__ __align__(16) unsigned short sV[64 * 64];
    __shared__ __align__(16) unsigned short sK[64 * 64];
    __shared__ float sKs[256];

    f32x4 acc[2][2];
    #pragma unroll
    for (int i = 0; i < 2; i++)
        #pragma unroll
        for (int j = 0; j < 2; j++) acc[i][j] = (f32x4){0.f, 0.f, 0.f, 0.f};
    float ks = 0.f;
    const int dks = tid >> 2, sgks = tid & 3;
    size_t base = (size_t)bh * 64 * 4096 + sc * 256;

    for (int kb = 0; kb < 4; kb++) {           // 4 x 64 s
        int s0 = kb * 64;
        #pragma unroll
        for (int t = 0; t < 2; t++) {
            int r0 = t * 32 + wave * 8;
            load_lds16(&vT[base + (size_t)(r0 + rsub) * 4096 + s0 + coff], &sV[r0 * 64]);
            load_lds16(&kT[base + (size_t)(r0 + rsub) * 4096 + s0 + coff], &sK[r0 * 64]);
        }
        __syncthreads();
        // ksum partial: thread owns (d=tid>>2, 16 s = 2 octets); unswizzle.
        #pragma unroll
        for (int gi = 0; gi < 2; gi++) {
            int gg = sgks * 2 + gi;
            int pg = ((gg ^ (dks & 7)) << 3);
            uint4 w = *(const uint4*)&sK[dks * 64 + pg];
            const unsigned int* wp = (const unsigned int*)&w;
            #pragma unroll
            for (int i2 = 0; i2 < 4; i2++) {
                ks += __builtin_bit_cast(float, wp[i2] << 16);
                ks += __builtin_bit_cast(float, wp[i2] & 0xFFFF0000u);
            }
        }
        #pragma unroll
        for (int ko = 0; ko < 64; ko += 32) {
            bf16x8 af[2], bfr[2];
            int pg = ((quad + (ko >> 3)) ^ (l16 & 7)) << 3;
            #pragma unroll
            for (int f = 0; f < 2; f++)
                af[f] = *(const bf16x8*)&sV[(wm * 32 + f * 16 + l16) * 64 + pg];
            #pragma unroll
            for (int f = 0; f < 2; f++)
                bfr[f] = *(const bf16x8*)&sK[(wn * 32 + f * 16 + l16) * 64 + pg];
            #pragma unroll
            for (int i = 0; i < 2; i++)
                #pragma unroll
                for (int j = 0; j < 2; j++)
                    acc[i][j] = __builtin_amdgcn_mfma_f32_16x16x32_bf16(af[i], bfr[j], acc[i][j], 0, 0, 0);
        }
        __syncthreads();
    }
    // write fp32 partial: kvp[sc][bh][m*64+d]
    float* kvout = kvp + ((size_t)sc * 64 + bh) * 4096;
    #pragma unroll
    for (int i = 0; i < 2; i++)
        #pragma unroll
        for (int j = 0; j < 2; j++)
            #pragma unroll
            for (int r = 0; r < 4; r++) {
                int m = wm * 32 + i * 16 + quad * 4 + r;
                int d = wn * 32 + j * 16 + l16;
                kvout[m * 64 + d] = acc[i][j][r];
            }
    sKs[tid] = ks;
    __syncthreads();
    if (tid < 64)
        ksp[((size_t)sc * 64 + bh) * 64 + tid] =
            sKs[tid * 4] + sKs[tid * 4 + 1] + sKs[tid * 4 + 2] + sKs[tid * 4 + 3];
}

// ---------------- mid: ksum reduce + z precompute + kv reduce ----------------
// grid: 512 blocks = bh(64) x chunk(8); chunk==0 blocks also reduce kv.
__global__ __launch_bounds__(256) void mid_kernel(
        const float* __restrict__ kvp, const float* __restrict__ ksp,
        const unsigned short* __restrict__ qb,
        unsigned short* __restrict__ kvb, float* __restrict__ zb) {
    int bh = blockIdx.x >> 3, chunk = blockIdx.x & 7;
    int b = bh >> 3, h = bh & 7;
    int tid = threadIdx.x;
    __shared__ float sKsum[64];
    if (tid < 64) {
        float s = 0.f;
        #pragma unroll
        for (int sc = 0; sc < 16; sc++) s += ksp[((size_t)sc * 64 + bh) * 64 + tid];
        sKsum[tid] = s;
    }
    __syncthreads();
    int seg = tid & 7, rsub = tid >> 3;     // 32 rows per pass, 8 lanes per row
    float ks8[8];
    #pragma unroll
    for (int j = 0; j < 8; j++) ks8[j] = sKsum[seg * 8 + j];
    #pragma unroll
    for (int p = 0; p < 16; p++) {
        int row = chunk * 512 + p * 32 + rsub;
        uint4 w = *(const uint4*)&qb[((size_t)(b * 4096 + row)) * 512 + h * 64 + seg * 8];
        const unsigned int* qp = (const unsigned int*)&w;
        float d = 0.f;
        #pragma unroll
        for (int i = 0; i < 4; i++) {
            d += __builtin_bit_cast(float, qp[i] << 16)        * ks8[2*i];
            d += __builtin_bit_cast(float, qp[i] & 0xFFFF0000u) * ks8[2*i+1];
        }
        d += __shfl_xor(d, 1, 64);
        d += __shfl_xor(d, 2, 64);
        d += __shfl_xor(d, 4, 64);
        if (seg == 0) zb[h * 32768 + b * 4096 + row] = 1.f / (d + 1e-6f);
    }
    if (chunk == 0) {
        #pragma unroll
        for (int i = 0; i < 4; i++) {
            int idx = (tid + i * 256) * 4;
            float s0 = 0.f, s1 = 0.f, s2 = 0.f, s3 = 0.f;
            #pragma unroll
            for (int sc = 0; sc < 16; sc++) {
                float4 v = *(const float4*)&kvp[((size_t)sc * 64 + bh) * 4096 + idx];
                s0 += v.x; s1 += v.y; s2 += v.z; s3 += v.w;
            }
            ushort4 o; o.x = f2b(s0); o.y = f2b(s1); o.z = f2b(s2); o.w = f2b(s3);
            *(ushort4*)&kvb[(size_t)bh * 4096 + idx] = o;
        }
    }
}

// ---------------- fused out1 + output GEMM -----------------------------------
// grid: 1024 1-D, XCD-swizzled (4 ntile blocks of one mtile -> same XCD).
__global__ __launch_bounds__(256, 2) void fused_out_kernel(
        const unsigned short* __restrict__ qb,
        const unsigned short* __restrict__ kvb, const float* __restrict__ zb,
        const unsigned short* __restrict__ wto, const float* __restrict__ bo,
        float* __restrict__ out) {
    int g = blockIdx.x;
    int xcd = g & 7, slot = g >> 3;            // slot 0..127
    int mtile = xcd * 32 + (slot >> 2);
    int ntile = slot & 3;

    __shared__ __align__(16) unsigned short sQ[128 * 64];
    __shared__ __align__(16) unsigned short sWo[128 * 64];
    __shared__ __align__(16) unsigned short sKV[64 * 64];
    __shared__ __align__(16) unsigned short sO1[128 * 64];
    __shared__ float sZ[128];
    const int tid  = threadIdx.x;
    const int wave = tid >> 6, lane = tid & 63;
    const int wm = wave >> 1, wn = wave & 1;
    const int quad = lane >> 4, l16 = lane & 15;
    const int mbase = mtile * 128, nbase = ntile * 128;
    const int b = mtile >> 5;
    const int rsub = lane >> 3;
    const int coff = (((lane & 7) ^ rsub) << 3);

    f32x4 accm[4][4];
    #pragma unroll
    for (int i = 0; i < 4; i++)
        #pragma unroll
        for (int j = 0; j < 4; j++) accm[i][j] = (f32x4){0.f, 0.f, 0.f, 0.f};

    for (int h = 0; h < 8; h++) {
        #pragma unroll
        for (int t = 0; t < 4; t++) {
            int r0 = t * 32 + wave * 8;
            load_lds16(&qb[(size_t)(mbase + r0 + rsub) * 512 + h * 64 + coff], &sQ[r0 * 64]);
            load_lds16(&wto[(size_t)(nbase + r0 + rsub) * 512 + h * 64 + coff], &sWo[r0 * 64]);
        }
        #pragma unroll
        for (int t = 0; t < 2; t++) {
            int r0 = t * 32 + wave * 8;
            load_lds16(&kvb[(size_t)(b * 8 + h) * 4096 + (r0 + rsub) * 64 + coff], &sKV[r0 * 64]);
        }
        if (tid < 128) sZ[tid] = zb[h * 32768 + mbase + tid];
        __syncthreads();
        // o1 = q_h @ kv_h^T  (wave computes 64 rows x 32 m-cols)
        f32x4 acco[4][2];
        #pragma unroll
        for (int f = 0; f < 4; f++)
            #pragma unroll
            for (int j = 0; j < 2; j++) acco[f][j] = (f32x4){0.f, 0.f, 0.f, 0.f};
        #pragma unroll
        for (int ko = 0; ko < 64; ko += 32) {
            bf16x8 af[4], bfr[2];
            int pg = ((quad + (ko >> 3)) ^ (l16 & 7)) << 3;
            #pragma unroll
            for (int f = 0; f < 4; f++)
                af[f] = *(const bf16x8*)&sQ[(wm * 64 + f * 16 + l16) * 64 + pg];
            #pragma unroll
            for (int j = 0; j < 2; j++)
                bfr[j] = *(const bf16x8*)&sKV[(wn * 32 + j * 16 + l16) * 64 + pg];
            #pragma unroll
            for (int f = 0; f < 4; f++)
                #pragma unroll
                for (int j = 0; j < 2; j++)
                    acco[f][j] = __builtin_amdgcn_mfma_f32_16x16x32_bf16(af[f], bfr[j], acco[f][j], 0, 0, 0);
        }
        // scale by z, write to sO1 (swizzled A-layout)
        #pragma unroll
        for (int f = 0; f < 4; f++)
            #pragma unroll
            for (int j = 0; j < 2; j++)
                #pragma unroll
                for (int r = 0; r < 4; r++) {
                    int row = wm * 64 + f * 16 + quad * 4 + r;
                    int col = wn * 32 + j * 16 + l16;
                    float v = acco[f][j][r] * sZ[row];
                    int grp = col >> 3;
                    sO1[row * 64 + ((grp ^ (row & 7)) << 3) + (col & 7)] = f2b(v);
                }
        __syncthreads();
        // accumulate o1_h @ Wo_h
        #pragma unroll
        for (int ko = 0; ko < 64; ko += 32) {
            bf16x8 af[4], bfr[4];
            int pg = ((quad + (ko >> 3)) ^ (l16 & 7)) << 3;
            #pragma unroll
            for (int f = 0; f < 4; f++)
                af[f] = *(const bf16x8*)&sO1[(wm * 64 + f * 16 + l16) * 64 + pg];
            #pragma unroll
            for (int f = 0; f < 4; f++)
                bfr[f] = *(const bf16x8*)&sWo[(wn * 64 + f * 16 + l16) * 64 + pg];
            #pragma unroll
            for (int i = 0; i < 4; i++)
                #pragma unroll
                for (int j = 0; j < 4; j++)
                    accm[i][j] = __builtin_amdgcn_mfma_f32_16x16x32_bf16(af[i], bfr[j], accm[i][j], 0, 0, 0);
        }
        __syncthreads();
    }
    #pragma unroll
    for (int i = 0; i < 4; i++)
        #pragma unroll
        for (int j = 0; j < 4; j++) {
            int gcol = nbase + wn * 64 + j * 16 + l16;
            float bv = bo[gcol];
            #pragma unroll
            for (int r = 0; r < 4; r++) {
                int grow = mbase + wm * 64 + i * 16 + quad * 4 + r;
                out[(size_t)grow * 512 + gcol] = accm[i][j][r] + bv;
            }
        }
}

// ---------------- launch -----------------------------------------------------
extern "C" void kernel_launch(void* const* d_in, const int* in_sizes, int n_in,
                              void* d_out, int out_size, void* d_ws, size_t ws_size,
                              hipStream_t stream) {
    const float* x  = (const float*)d_in[0];
    const float* Wq = (const float*)d_in[1];
    const float* bq = (const float*)d_in[2];
    const float* Wk = (const float*)d_in[3];
    const float* bk = (const float*)d_in[4];
    const float* Wv = (const float*)d_in[5];
    const float* bv = (const float*)d_in[6];
    const float* Wo = (const float*)d_in[7];
    const float* bo = (const float*)d_in[8];
    float* out = (float*)d_out;

    char* wsb = (char*)d_ws;
    char* ob  = (char*)d_out;
    // d_out scratch (dead before fused_out writes):
    unsigned short* vT  = (unsigned short*)ob;                    // 32 MB
    unsigned short* xb  = (unsigned short*)(ob + 33554432ull);    // 32 MB, dead after gemm_qkv
    float*          kvp = (float*)(ob + 33554432ull);             // 16.8 MB, overlays xb
    // ws:
    unsigned short* qb  = (unsigned short*)wsb;                   // 32 MB
    unsigned short* kT  = (unsigned short*)(wsb + 33554432ull);   // 32 MB
    unsigned short* wt  = (unsigned short*)(wsb + 67108864ull);   // 2 MB
    float*          ksp = (float*)(wsb + 69206016ull);            // 256 KB
    unsigned short* kvb = (unsigned short*)(wsb + 69468160ull);   // 512 KB
    float*          zb  = (float*)(wsb + 69992448ull);            // 1 MB

    prep_kernel<<<16640, 256, 0, stream>>>(x, Wq, Wk, Wv, Wo, xb, wt);
    gemm_qkv_kernel<<<768, 512, 0, stream>>>(xb, wt, bq, bk, bv, qb, kT, vT);
    kv_kernel<<<1024, 256, 0, stream>>>(kT, vT, kvp, ksp);
    mid_kernel<<<512, 256, 0, stream>>>(kvp, ksp, qb, kvb, zb);
    fused_out_kernel<<<1024, 256, 0, stream>>>(qb, kvb, zb,
            wt + 3ull * 512 * 512, bo, out);
}

// Round 4
// 259.817 us; speedup vs baseline: 1.0388x; 1.0342x over previous
//
#include <hip/hip_runtime.h>
#include <hip/hip_bf16.h>

// B=8, S=4096, E=512, QKV=512, H=8, D=64, M=B*S=32768
// R7 pipeline (5 launches):
//   prep:      x fp32 -> bf16 (d_out hi half) + W transposes -> wt (ws) + zero ksg
//   gemm_qkv:  q = act(x@Wq+b) row-major (ws); k,v stored ONLY TRANSPOSED
//              kT/vT[bh][d|m][4096] bf16 (k act'd), XCD-swizzled grid.
//              k-blocks also atomically accumulate ksum (fp32) into ksg[b][gcol].
//   kv:        MFMA GEMM over s: kv_part[m][d] = sum_s vT[m][s]*kT[d][s]
//   mid:       reduce kv partials -> bf16 kvb
//   fused_out: per 128x128 out block: loop h { z from sQ x ksg (in-block),
//              o1_h = z*(q_h@kv_h^T) in LDS, accumulate o1_h @ Wo_h } + bias
//              -> d_out fp32 (XCD-swizzled)
// Scratch:
//   d_out[0,32M):  vT (dead after kv), then final out rows
//   d_out[32,64M): xb (dead after gemm_qkv) -> kvp partials -> final out rows
//   ws: qb[0,32M) kT[32,64M) wt[64,66M) kvb/ksg[66,~66.5M)

typedef __bf16 bf16x8 __attribute__((ext_vector_type(8)));
typedef float  f32x4  __attribute__((ext_vector_type(4)));

__device__ __forceinline__ float b2f(unsigned short u) {
    unsigned int x = ((unsigned int)u) << 16;
    return __builtin_bit_cast(float, x);
}
__device__ __forceinline__ unsigned short f2b(float f) {
    unsigned int u = __builtin_bit_cast(unsigned int, f);
    unsigned int r = (u + 0x7FFFu + ((u >> 16) & 1u)) >> 16;
    return (unsigned short)r;
}
__device__ __forceinline__ void load_lds16(const unsigned short* g, unsigned short* l) {
    __builtin_amdgcn_global_load_lds(
        (const __attribute__((address_space(1))) void*)g,
        (__attribute__((address_space(3))) void*)l, 16, 0, 0);
}

// ---------------- prep: W transpose (blocks 0..255) + x cvt (blocks 256..) ---
__global__ void prep_kernel(const float* __restrict__ x,
                            const float* __restrict__ w0, const float* __restrict__ w1,
                            const float* __restrict__ w2, const float* __restrict__ w3,
                            unsigned short* __restrict__ xb, unsigned short* __restrict__ wt,
                            float* __restrict__ ksg) {
    __shared__ float tile[64][65];
    int t = threadIdx.x;
    if (blockIdx.x >= 256) {
        int i = (blockIdx.x - 256) * 256 + t;   // < 4194304
        float4 v = ((const float4*)x)[i];
        ushort4 o;
        o.x = f2b(v.x); o.y = f2b(v.y); o.z = f2b(v.z); o.w = f2b(v.w);
        ((ushort4*)xb)[i] = o;
        return;
    }
    int idx = blockIdx.x;
    if (idx < 16) ksg[idx * 256 + t] = 0.f;     // zero ksum accumulator (4096 f32)
    int bz = idx >> 6, by = (idx >> 3) & 7, bx = idx & 7;
    const float* src = (bz == 0) ? w0 : (bz == 1) ? w1 : (bz == 2) ? w2 : w3;
    unsigned short* dst = wt + (size_t)bz * 512 * 512;
    int rb = by * 64, cb = bx * 64;
    #pragma unroll
    for (int i = 0; i < 16; i++) {
        int c = t + i * 256; int r = c >> 6, cc = c & 63;
        tile[r][cc] = src[(rb + r) * 512 + cb + cc];
    }
    __syncthreads();
    #pragma unroll
    for (int i = 0; i < 16; i++) {
        int c = t + i * 256; int r = c >> 6, cc = c & 63;
        dst[(cb + r) * 512 + rb + cc] = f2b(tile[cc][r]);   // Wt[n][k]=W[k][n]
    }
}

// ---------------- gemm_qkv: 128x128 MFMA, q row-major / k,v transposed -------
// grid: 3072 1-D, XCD-swizzled: all 12 (tensor,ntile) blocks of one mtile get
// equal blockIdx%8 -> same XCD -> A-tile L2 hit.
// k-blocks (tensor==1) also accumulate fp32 column sums -> atomicAdd ksg.
__global__ __launch_bounds__(256, 4) void gemm_qkv_kernel(
        const unsigned short* __restrict__ xb, const unsigned short* __restrict__ wt,
        const float* __restrict__ bq, const float* __restrict__ bk, const float* __restrict__ bv,
        unsigned short* __restrict__ qb, unsigned short* __restrict__ kT,
        unsigned short* __restrict__ vT, float* __restrict__ ksg) {
    int g = blockIdx.x;
    int xcd = g & 7, slot = g >> 3;            // slot 0..383
    int mtile = xcd * 32 + slot / 12;
    int tn = slot % 12;
    int tensor = tn >> 2, ntile = tn & 3;
    const unsigned short* Bt = wt + (size_t)tensor * 512 * 512;
    const float* bias = tensor == 0 ? bq : tensor == 1 ? bk : bv;
    bool act = tensor < 2;

    __shared__ __align__(16) unsigned short sA[128 * 64];
    __shared__ __align__(16) unsigned short sB[128 * 64];
    const int tid  = threadIdx.x;
    const int wave = tid >> 6, lane = tid & 63;
    const int wm = wave >> 1, wn = wave & 1;
    const int quad = lane >> 4, l16 = lane & 15;
    const int mbase = mtile * 128, nbase = ntile * 128;
    const int rsub = lane >> 3;
    const int coff = (((lane & 7) ^ rsub) << 3);

    f32x4 acc[4][4];
    #pragma unroll
    for (int i = 0; i < 4; i++)
        #pragma unroll
        for (int j = 0; j < 4; j++) acc[i][j] = (f32x4){0.f, 0.f, 0.f, 0.f};

    for (int kb = 0; kb < 512; kb += 64) {
        #pragma unroll
        for (int t = 0; t < 4; t++) {
            int r0 = t * 32 + wave * 8;
            load_lds16(&xb[(size_t)(mbase + r0 + rsub) * 512 + kb + coff], &sA[r0 * 64]);
            load_lds16(&Bt[(size_t)(nbase + r0 + rsub) * 512 + kb + coff], &sB[r0 * 64]);
        }
        __syncthreads();
        #pragma unroll
        for (int ko = 0; ko < 64; ko += 32) {
            bf16x8 af[4], bfr[4];
            int pg = ((quad + (ko >> 3)) ^ (l16 & 7)) << 3;
            #pragma unroll
            for (int f = 0; f < 4; f++)
                af[f] = *(const bf16x8*)&sA[(wm * 64 + f * 16 + l16) * 64 + pg];
            #pragma unroll
            for (int f = 0; f < 4; f++)
                bfr[f] = *(const bf16x8*)&sB[(wn * 64 + f * 16 + l16) * 64 + pg];
            #pragma unroll
            for (int i = 0; i < 4; i++)
                #pragma unroll
                for (int j = 0; j < 4; j++)
                    acc[i][j] = __builtin_amdgcn_mfma_f32_16x16x32_bf16(af[i], bfr[j], acc[i][j], 0, 0, 0);
        }
        __syncthreads();
    }
    // epilogue. C/D layout: col = lane&15, row = quad*4+reg (m89-verified).
    if (tensor == 0) {
        #pragma unroll
        for (int i = 0; i < 4; i++)
            #pragma unroll
            for (int j = 0; j < 4; j++) {
                int gcol = nbase + wn * 64 + j * 16 + l16;
                float bv = bias[gcol];
                #pragma unroll
                for (int r = 0; r < 4; r++) {
                    int grow = mbase + wm * 64 + i * 16 + quad * 4 + r;
                    float v = acc[i][j][r] + bv;
                    v = v > 0.f ? v + 1.f : __expf(v);
                    qb[(size_t)grow * 512 + gcol] = f2b(v);
                }
            }
    } else {
        // transposed store: T[((b*8+h)*64 + d)*4096 + s], 4 consecutive s
        // (the 4 acc regs = rows quad*4+0..3) packed into one ushort4.
        unsigned short* T = (tensor == 1) ? kT : vT;
        float csum[4] = {0.f, 0.f, 0.f, 0.f};
        #pragma unroll
        for (int i = 0; i < 4; i++)
            #pragma unroll
            for (int j = 0; j < 4; j++) {
                int gcol = nbase + wn * 64 + j * 16 + l16;   // 0..511
                int h = gcol >> 6, d = gcol & 63;
                float bv = bias[gcol];
                int grow0 = mbase + wm * 64 + i * 16 + quad * 4;
                int b = grow0 >> 12, s0 = grow0 & 4095;
                ushort4 o;
                #pragma unroll
                for (int r = 0; r < 4; r++) {
                    float v = acc[i][j][r] + bv;
                    if (act) { v = v > 0.f ? v + 1.f : __expf(v); csum[j] += v; }
                    ((unsigned short*)&o)[r] = f2b(v);
                }
                *(ushort4*)&T[(((size_t)b * 8 + h) * 64 + d) * 4096 + s0] = o;
            }
        if (act) {   // tensor==1 (k): fp32 ksum accumulation, pre-bf16-rounding
            int b = mbase >> 12;
            #pragma unroll
            for (int j = 0; j < 4; j++) {
                float s = csum[j];
                s += __shfl_xor(s, 16, 64);   // quad reduce (rows quad*4+r)
                s += __shfl_xor(s, 32, 64);
                if (quad == 0) {
                    int gcol = nbase + wn * 64 + j * 16 + l16;
                    atomicAdd(&ksg[b * 512 + gcol], s);
                }
            }
        }
    }
}

// ---------------- kv: MFMA GEMM over s --------------------------------------
// grid: x = bh(64) * sc(16); block: C[64 m][64 d] partial over 256 s.
// A = vT rows (m), B = kT rows (d), both K-major -> m97 staging applies.
__global__ __launch_bounds__(256, 4) void kv_kernel(
        const unsigned short* __restrict__ kT, const unsigned short* __restrict__ vT,
        float* __restrict__ kvp) {
    int bh = blockIdx.x >> 4, sc = blockIdx.x & 15;
    const int tid = threadIdx.x;
    const int wave = tid >> 6, lane = tid & 63;
    const int wm = wave >> 1, wn = wave & 1;
    const int quad = lane >> 4, l16 = lane & 15;
    const int rsub = lane >> 3;
    const int coff = (((lane & 7) ^ rsub) << 3);
    __shared__ __align__(16) unsigned short sV[64 * 64];
    __shared__ __align__(16) unsigned short sK[64 * 64];

    f32x4 acc[2][2];
    #pragma unroll
    for (int i = 0; i < 2; i++)
        #pragma unroll
        for (int j = 0; j < 2; j++) acc[i][j] = (f32x4){0.f, 0.f, 0.f, 0.f};
    size_t base = (size_t)bh * 64 * 4096 + sc * 256;

    for (int kb = 0; kb < 4; kb++) {           // 4 x 64 s
        int s0 = kb * 64;
        #pragma unroll
        for (int t = 0; t < 2; t++) {
            int r0 = t * 32 + wave * 8;
            load_lds16(&vT[base + (size_t)(r0 + rsub) * 4096 + s0 + coff], &sV[r0 * 64]);
            load_lds16(&kT[base + (size_t)(r0 + rsub) * 4096 + s0 + coff], &sK[r0 * 64]);
        }
        __syncthreads();
        #pragma unroll
        for (int ko = 0; ko < 64; ko += 32) {
            bf16x8 af[2], bfr[2];
            int pg = ((quad + (ko >> 3)) ^ (l16 & 7)) << 3;
            #pragma unroll
            for (int f = 0; f < 2; f++)
                af[f] = *(const bf16x8*)&sV[(wm * 32 + f * 16 + l16) * 64 + pg];
            #pragma unroll
            for (int f = 0; f < 2; f++)
                bfr[f] = *(const bf16x8*)&sK[(wn * 32 + f * 16 + l16) * 64 + pg];
            #pragma unroll
            for (int i = 0; i < 2; i++)
                #pragma unroll
                for (int j = 0; j < 2; j++)
                    acc[i][j] = __builtin_amdgcn_mfma_f32_16x16x32_bf16(af[i], bfr[j], acc[i][j], 0, 0, 0);
        }
        __syncthreads();
    }
    // write fp32 partial: kvp[sc][bh][m*64+d]
    float* kvout = kvp + ((size_t)sc * 64 + bh) * 4096;
    #pragma unroll
    for (int i = 0; i < 2; i++)
        #pragma unroll
        for (int j = 0; j < 2; j++)
            #pragma unroll
            for (int r = 0; r < 4; r++) {
                int m = wm * 32 + i * 16 + quad * 4 + r;
                int d = wn * 32 + j * 16 + l16;
                kvout[m * 64 + d] = acc[i][j][r];
            }
}

// ---------------- mid: kv partial reduce -> bf16 -----------------------------
// grid: 256 blocks = bh(64) x part(4); thread reduces one float4 over 16 sc.
__global__ __launch_bounds__(256) void mid_kernel(
        const float* __restrict__ kvp, unsigned short* __restrict__ kvb) {
    int bh = blockIdx.x >> 2, part = blockIdx.x & 3;
    int tid = threadIdx.x;
    int idx = (part * 256 + tid) * 4;
    float s0 = 0.f, s1 = 0.f, s2 = 0.f, s3 = 0.f;
    #pragma unroll
    for (int sc = 0; sc < 16; sc++) {
        float4 v = *(const float4*)&kvp[((size_t)sc * 64 + bh) * 4096 + idx];
        s0 += v.x; s1 += v.y; s2 += v.z; s3 += v.w;
    }
    ushort4 o; o.x = f2b(s0); o.y = f2b(s1); o.z = f2b(s2); o.w = f2b(s3);
    *(ushort4*)&kvb[(size_t)bh * 4096 + idx] = o;
}

// ---------------- fused out1 + output GEMM -----------------------------------
// grid: 1024 1-D, XCD-swizzled (4 ntile blocks of one mtile -> same XCD).
// z computed in-block per h from staged sQ and fp32 ksum (ksg).
__global__ __launch_bounds__(256, 2) void fused_out_kernel(
        const unsigned short* __restrict__ qb,
        const unsigned short* __restrict__ kvb, const float* __restrict__ ksg,
        const unsigned short* __restrict__ wto, const float* __restrict__ bo,
        float* __restrict__ out) {
    int g = blockIdx.x;
    int xcd = g & 7, slot = g >> 3;            // slot 0..127
    int mtile = xcd * 32 + (slot >> 2);
    int ntile = slot & 3;

    __shared__ __align__(16) unsigned short sQ[128 * 64];
    __shared__ __align__(16) unsigned short sWo[128 * 64];
    __shared__ __align__(16) unsigned short sKV[64 * 64];
    __shared__ __align__(16) unsigned short sO1[128 * 64];
    __shared__ float sKsum[512];
    __shared__ float sZ[128];
    const int tid  = threadIdx.x;
    const int wave = tid >> 6, lane = tid & 63;
    const int wm = wave >> 1, wn = wave & 1;
    const int quad = lane >> 4, l16 = lane & 15;
    const int mbase = mtile * 128, nbase = ntile * 128;
    const int b = mtile >> 5;
    const int rsub = lane >> 3;
    const int coff = (((lane & 7) ^ rsub) << 3);

    // stage fp32 ksum for this b (512 cols = 8 h x 64 d)
    sKsum[tid]       = ksg[b * 512 + tid];
    sKsum[tid + 256] = ksg[b * 512 + 256 + tid];

    f32x4 accm[4][4];
    #pragma unroll
    for (int i = 0; i < 4; i++)
        #pragma unroll
        for (int j = 0; j < 4; j++) accm[i][j] = (f32x4){0.f, 0.f, 0.f, 0.f};

    for (int h = 0; h < 8; h++) {
        #pragma unroll
        for (int t = 0; t < 4; t++) {
            int r0 = t * 32 + wave * 8;
            load_lds16(&qb[(size_t)(mbase + r0 + rsub) * 512 + h * 64 + coff], &sQ[r0 * 64]);
            load_lds16(&wto[(size_t)(nbase + r0 + rsub) * 512 + h * 64 + coff], &sWo[r0 * 64]);
        }
        #pragma unroll
        for (int t = 0; t < 2; t++) {
            int r0 = t * 32 + wave * 8;
            load_lds16(&kvb[(size_t)(b * 8 + h) * 4096 + (r0 + rsub) * 64 + coff], &sKV[r0 * 64]);
        }
        __syncthreads();
        // z = 1/(q_h . ksum_h + eps) per row, from swizzled sQ (fp32 accum).
        {
            int row = tid >> 1, half = tid & 1;
            const float* ksh = &sKsum[h * 64];
            float dsum = 0.f;
            #pragma unroll
            for (int g2 = 0; g2 < 4; g2++) {
                int G = half * 4 + g2;                       // global octet
                uint4 w = *(const uint4*)&sQ[row * 64 + ((G ^ (row & 7)) << 3)];
                const unsigned int* qp = (const unsigned int*)&w;
                #pragma unroll
                for (int u = 0; u < 4; u++) {
                    int c = G * 8 + u * 2;
                    dsum += __builtin_bit_cast(float, qp[u] << 16)        * ksh[c];
                    dsum += __builtin_bit_cast(float, qp[u] & 0xFFFF0000u) * ksh[c + 1];
                }
            }
            dsum += __shfl_xor(dsum, 1, 64);
            if (!half) sZ[row] = 1.f / (dsum + 1e-6f);
        }
        __syncthreads();
        // o1 = q_h @ kv_h^T  (wave computes 64 rows x 32 m-cols)
        f32x4 acco[4][2];
        #pragma unroll
        for (int f = 0; f < 4; f++)
            #pragma unroll
            for (int j = 0; j < 2; j++) acco[f][j] = (f32x4){0.f, 0.f, 0.f, 0.f};
        #pragma unroll
        for (int ko = 0; ko < 64; ko += 32) {
            bf16x8 af[4], bfr[2];
            int pg = ((quad + (ko >> 3)) ^ (l16 & 7)) << 3;
            #pragma unroll
            for (int f = 0; f < 4; f++)
                af[f] = *(const bf16x8*)&sQ[(wm * 64 + f * 16 + l16) * 64 + pg];
            #pragma unroll
            for (int j = 0; j < 2; j++)
                bfr[j] = *(const bf16x8*)&sKV[(wn * 32 + j * 16 + l16) * 64 + pg];
            #pragma unroll
            for (int f = 0; f < 4; f++)
                #pragma unroll
                for (int j = 0; j < 2; j++)
                    acco[f][j] = __builtin_amdgcn_mfma_f32_16x16x32_bf16(af[f], bfr[j], acco[f][j], 0, 0, 0);
        }
        // scale by z, write to sO1 (swizzled A-layout)
        #pragma unroll
        for (int f = 0; f < 4; f++)
            #pragma unroll
            for (int j = 0; j < 2; j++)
                #pragma unroll
                for (int r = 0; r < 4; r++) {
                    int row = wm * 64 + f * 16 + quad * 4 + r;
                    int col = wn * 32 + j * 16 + l16;
                    float v = acco[f][j][r] * sZ[row];
                    int grp = col >> 3;
                    sO1[row * 64 + ((grp ^ (row & 7)) << 3) + (col & 7)] = f2b(v);
                }
        __syncthreads();
        // accumulate o1_h @ Wo_h
        #pragma unroll
        for (int ko = 0; ko < 64; ko += 32) {
            bf16x8 af[4], bfr[4];
            int pg = ((quad + (ko >> 3)) ^ (l16 & 7)) << 3;
            #pragma unroll
            for (int f = 0; f < 4; f++)
                af[f] = *(const bf16x8*)&sO1[(wm * 64 + f * 16 + l16) * 64 + pg];
            #pragma unroll
            for (int f = 0; f < 4; f++)
                bfr[f] = *(const bf16x8*)&sWo[(wn * 64 + f * 16 + l16) * 64 + pg];
            #pragma unroll
            for (int i = 0; i < 4; i++)
                #pragma unroll
                for (int j = 0; j < 4; j++)
                    accm[i][j] = __builtin_amdgcn_mfma_f32_16x16x32_bf16(af[i], bfr[j], accm[i][j], 0, 0, 0);
        }
        __syncthreads();
    }
    #pragma unroll
    for (int i = 0; i < 4; i++)
        #pragma unroll
        for (int j = 0; j < 4; j++) {
            int gcol = nbase + wn * 64 + j * 16 + l16;
            float bv = bo[gcol];
            #pragma unroll
            for (int r = 0; r < 4; r++) {
                int grow = mbase + wm * 64 + i * 16 + quad * 4 + r;
                out[(size_t)grow * 512 + gcol] = accm[i][j][r] + bv;
            }
        }
}

// ---------------- launch -----------------------------------------------------
extern "C" void kernel_launch(void* const* d_in, const int* in_sizes, int n_in,
                              void* d_out, int out_size, void* d_ws, size_t ws_size,
                              hipStream_t stream) {
    const float* x  = (const float*)d_in[0];
    const float* Wq = (const float*)d_in[1];
    const float* bq = (const float*)d_in[2];
    const float* Wk = (const float*)d_in[3];
    const float* bk = (const float*)d_in[4];
    const float* Wv = (const float*)d_in[5];
    const float* bv = (const float*)d_in[6];
    const float* Wo = (const float*)d_in[7];
    const float* bo = (const float*)d_in[8];
    float* out = (float*)d_out;

    char* wsb = (char*)d_ws;
    char* ob  = (char*)d_out;
    // d_out scratch (dead before fused_out writes):
    unsigned short* vT  = (unsigned short*)ob;                    // 32 MB
    unsigned short* xb  = (unsigned short*)(ob + 33554432ull);    // 32 MB, dead after gemm_qkv
    float*          kvp = (float*)(ob + 33554432ull);             // 16.8 MB, overlays xb
    // ws:
    unsigned short* qb  = (unsigned short*)wsb;                   // 32 MB
    unsigned short* kT  = (unsigned short*)(wsb + 33554432ull);   // 32 MB
    unsigned short* wt  = (unsigned short*)(wsb + 67108864ull);   // 2 MB
    unsigned short* kvb = (unsigned short*)(wsb + 69206016ull);   // 512 KB
    float*          ksg = (float*)(wsb + 69730304ull);            // 16 KB

    prep_kernel<<<16640, 256, 0, stream>>>(x, Wq, Wk, Wv, Wo, xb, wt, ksg);
    gemm_qkv_kernel<<<3072, 256, 0, stream>>>(xb, wt, bq, bk, bv, qb, kT, vT, ksg);
    kv_kernel<<<1024, 256, 0, stream>>>(kT, vT, kvp);
    mid_kernel<<<256, 256, 0, stream>>>(kvp, kvb);
    fused_out_kernel<<<1024, 256, 0, stream>>>(qb, kvb, ksg,
            wt + 3ull * 512 * 512, bo, out);
}

// Round 5
// 242.455 us; speedup vs baseline: 1.1132x; 1.0716x over previous
//
#include <hip/hip_runtime.h>
#include <hip/hip_bf16.h>

// B=8, S=4096, E=512, QKV=512, H=8, D=64, M=B*S=32768
// R8 pipeline (5 launches):
//   prep:      x fp32 -> bf16 (d_out hi half) + W transposes -> wt (ws) + zero ksg
//   gemm_qkv:  q = act(x@Wq+b) row-major (ws); k,v stored ONLY TRANSPOSED
//              kT/vT[bh][d|m][4096] bf16 (k act'd), XCD-swizzled grid.
//              k-blocks also atomically accumulate ksum (fp32) into ksg[b][gcol].
//   kv:        MFMA GEMM over s (sc=8 chunks of 512): kv_part[m][d]
//   mid:       reduce kv partials (8) -> bf16 kvb
//   fused_out: per 128x256 out block (2 ntiles, o1 computed ONCE per mtile-half):
//              loop h { z from sQ x ksg, o1_h = z*(q_h@kv_h^T) in LDS,
//              accumulate o1_h @ Wo_h for both ntiles } + bias -> out fp32
// Scratch:
//   d_out[0,32M):  vT (dead after kv), then final out rows
//   d_out[32,64M): xb (dead after gemm_qkv) -> kvp partials -> final out rows
//   ws: qb[0,32M) kT[32,64M) wt[64,66M) kvb/ksg[66,~66.5M)

typedef __bf16 bf16x8 __attribute__((ext_vector_type(8)));
typedef float  f32x4  __attribute__((ext_vector_type(4)));

__device__ __forceinline__ float b2f(unsigned short u) {
    unsigned int x = ((unsigned int)u) << 16;
    return __builtin_bit_cast(float, x);
}
__device__ __forceinline__ unsigned short f2b(float f) {
    unsigned int u = __builtin_bit_cast(unsigned int, f);
    unsigned int r = (u + 0x7FFFu + ((u >> 16) & 1u)) >> 16;
    return (unsigned short)r;
}
__device__ __forceinline__ void load_lds16(const unsigned short* g, unsigned short* l) {
    __builtin_amdgcn_global_load_lds(
        (const __attribute__((address_space(1))) void*)g,
        (__attribute__((address_space(3))) void*)l, 16, 0, 0);
}

// ---------------- prep: W transpose (blocks 0..255) + x cvt (blocks 256..) ---
__global__ void prep_kernel(const float* __restrict__ x,
                            const float* __restrict__ w0, const float* __restrict__ w1,
                            const float* __restrict__ w2, const float* __restrict__ w3,
                            unsigned short* __restrict__ xb, unsigned short* __restrict__ wt,
                            float* __restrict__ ksg) {
    __shared__ float tile[64][65];
    int t = threadIdx.x;
    if (blockIdx.x >= 256) {
        int i = (blockIdx.x - 256) * 256 + t;   // < 4194304
        float4 v = ((const float4*)x)[i];
        ushort4 o;
        o.x = f2b(v.x); o.y = f2b(v.y); o.z = f2b(v.z); o.w = f2b(v.w);
        ((ushort4*)xb)[i] = o;
        return;
    }
    int idx = blockIdx.x;
    if (idx < 16) ksg[idx * 256 + t] = 0.f;     // zero ksum accumulator (4096 f32)
    int bz = idx >> 6, by = (idx >> 3) & 7, bx = idx & 7;
    const float* src = (bz == 0) ? w0 : (bz == 1) ? w1 : (bz == 2) ? w2 : w3;
    unsigned short* dst = wt + (size_t)bz * 512 * 512;
    int rb = by * 64, cb = bx * 64;
    #pragma unroll
    for (int i = 0; i < 16; i++) {
        int c = t + i * 256; int r = c >> 6, cc = c & 63;
        tile[r][cc] = src[(rb + r) * 512 + cb + cc];
    }
    __syncthreads();
    #pragma unroll
    for (int i = 0; i < 16; i++) {
        int c = t + i * 256; int r = c >> 6, cc = c & 63;
        dst[(cb + r) * 512 + rb + cc] = f2b(tile[cc][r]);   // Wt[n][k]=W[k][n]
    }
}

// ---------------- gemm_qkv: 128x128 MFMA, q row-major / k,v transposed -------
// grid: 3072 1-D, XCD-swizzled: all 12 (tensor,ntile) blocks of one mtile get
// equal blockIdx%8 -> same XCD -> A-tile L2 hit.
// k-blocks (tensor==1) also accumulate fp32 column sums -> atomicAdd ksg.
__global__ __launch_bounds__(256, 4) void gemm_qkv_kernel(
        const unsigned short* __restrict__ xb, const unsigned short* __restrict__ wt,
        const float* __restrict__ bq, const float* __restrict__ bk, const float* __restrict__ bv,
        unsigned short* __restrict__ qb, unsigned short* __restrict__ kT,
        unsigned short* __restrict__ vT, float* __restrict__ ksg) {
    int g = blockIdx.x;
    int xcd = g & 7, slot = g >> 3;            // slot 0..383
    int mtile = xcd * 32 + slot / 12;
    int tn = slot % 12;
    int tensor = tn >> 2, ntile = tn & 3;
    const unsigned short* Bt = wt + (size_t)tensor * 512 * 512;
    const float* bias = tensor == 0 ? bq : tensor == 1 ? bk : bv;
    bool act = tensor < 2;

    __shared__ __align__(16) unsigned short sA[128 * 64];
    __shared__ __align__(16) unsigned short sB[128 * 64];
    const int tid  = threadIdx.x;
    const int wave = tid >> 6, lane = tid & 63;
    const int wm = wave >> 1, wn = wave & 1;
    const int quad = lane >> 4, l16 = lane & 15;
    const int mbase = mtile * 128, nbase = ntile * 128;
    const int rsub = lane >> 3;
    const int coff = (((lane & 7) ^ rsub) << 3);

    f32x4 acc[4][4];
    #pragma unroll
    for (int i = 0; i < 4; i++)
        #pragma unroll
        for (int j = 0; j < 4; j++) acc[i][j] = (f32x4){0.f, 0.f, 0.f, 0.f};

    for (int kb = 0; kb < 512; kb += 64) {
        #pragma unroll
        for (int t = 0; t < 4; t++) {
            int r0 = t * 32 + wave * 8;
            load_lds16(&xb[(size_t)(mbase + r0 + rsub) * 512 + kb + coff], &sA[r0 * 64]);
            load_lds16(&Bt[(size_t)(nbase + r0 + rsub) * 512 + kb + coff], &sB[r0 * 64]);
        }
        __syncthreads();
        #pragma unroll
        for (int ko = 0; ko < 64; ko += 32) {
            bf16x8 af[4], bfr[4];
            int pg = ((quad + (ko >> 3)) ^ (l16 & 7)) << 3;
            #pragma unroll
            for (int f = 0; f < 4; f++)
                af[f] = *(const bf16x8*)&sA[(wm * 64 + f * 16 + l16) * 64 + pg];
            #pragma unroll
            for (int f = 0; f < 4; f++)
                bfr[f] = *(const bf16x8*)&sB[(wn * 64 + f * 16 + l16) * 64 + pg];
            #pragma unroll
            for (int i = 0; i < 4; i++)
                #pragma unroll
                for (int j = 0; j < 4; j++)
                    acc[i][j] = __builtin_amdgcn_mfma_f32_16x16x32_bf16(af[i], bfr[j], acc[i][j], 0, 0, 0);
        }
        __syncthreads();
    }
    // epilogue. C/D layout: col = lane&15, row = quad*4+reg (m89-verified).
    if (tensor == 0) {
        #pragma unroll
        for (int i = 0; i < 4; i++)
            #pragma unroll
            for (int j = 0; j < 4; j++) {
                int gcol = nbase + wn * 64 + j * 16 + l16;
                float bv = bias[gcol];
                #pragma unroll
                for (int r = 0; r < 4; r++) {
                    int grow = mbase + wm * 64 + i * 16 + quad * 4 + r;
                    float v = acc[i][j][r] + bv;
                    v = v > 0.f ? v + 1.f : __expf(v);
                    qb[(size_t)grow * 512 + gcol] = f2b(v);
                }
            }
    } else {
        // transposed store: T[((b*8+h)*64 + d)*4096 + s], 4 consecutive s
        // (the 4 acc regs = rows quad*4+0..3) packed into one ushort4.
        unsigned short* T = (tensor == 1) ? kT : vT;
        float csum[4] = {0.f, 0.f, 0.f, 0.f};
        #pragma unroll
        for (int i = 0; i < 4; i++)
            #pragma unroll
            for (int j = 0; j < 4; j++) {
                int gcol = nbase + wn * 64 + j * 16 + l16;   // 0..511
                int h = gcol >> 6, d = gcol & 63;
                float bv = bias[gcol];
                int grow0 = mbase + wm * 64 + i * 16 + quad * 4;
                int b = grow0 >> 12, s0 = grow0 & 4095;
                ushort4 o;
                #pragma unroll
                for (int r = 0; r < 4; r++) {
                    float v = acc[i][j][r] + bv;
                    if (act) { v = v > 0.f ? v + 1.f : __expf(v); csum[j] += v; }
                    ((unsigned short*)&o)[r] = f2b(v);
                }
                *(ushort4*)&T[(((size_t)b * 8 + h) * 64 + d) * 4096 + s0] = o;
            }
        if (act) {   // tensor==1 (k): fp32 ksum accumulation, pre-bf16-rounding
            int b = mbase >> 12;
            #pragma unroll
            for (int j = 0; j < 4; j++) {
                float s = csum[j];
                s += __shfl_xor(s, 16, 64);   // quad reduce (rows quad*4+r)
                s += __shfl_xor(s, 32, 64);
                if (quad == 0) {
                    int gcol = nbase + wn * 64 + j * 16 + l16;
                    atomicAdd(&ksg[b * 512 + gcol], s);
                }
            }
        }
    }
}

// ---------------- kv: MFMA GEMM over s --------------------------------------
// grid: x = bh(64) * sc(8); block: C[64 m][64 d] partial over 512 s.
// A = vT rows (m), B = kT rows (d), both K-major -> m97 staging applies.
__global__ __launch_bounds__(256, 4) void kv_kernel(
        const unsigned short* __restrict__ kT, const unsigned short* __restrict__ vT,
        float* __restrict__ kvp) {
    int bh = blockIdx.x >> 3, sc = blockIdx.x & 7;
    const int tid = threadIdx.x;
    const int wave = tid >> 6, lane = tid & 63;
    const int wm = wave >> 1, wn = wave & 1;
    const int quad = lane >> 4, l16 = lane & 15;
    const int rsub = lane >> 3;
    const int coff = (((lane & 7) ^ rsub) << 3);
    __shared__ __align__(16) unsigned short sV[64 * 64];
    __shared__ __align__(16) unsigned short sK[64 * 64];

    f32x4 acc[2][2];
    #pragma unroll
    for (int i = 0; i < 2; i++)
        #pragma unroll
        for (int j = 0; j < 2; j++) acc[i][j] = (f32x4){0.f, 0.f, 0.f, 0.f};
    size_t base = (size_t)bh * 64 * 4096 + sc * 512;

    for (int kb = 0; kb < 8; kb++) {           // 8 x 64 s
        int s0 = kb * 64;
        #pragma unroll
        for (int t = 0; t < 2; t++) {
            int r0 = t * 32 + wave * 8;
            load_lds16(&vT[base + (size_t)(r0 + rsub) * 4096 + s0 + coff], &sV[r0 * 64]);
            load_lds16(&kT[base + (size_t)(r0 + rsub) * 4096 + s0 + coff], &sK[r0 * 64]);
        }
        __syncthreads();
        #pragma unroll
        for (int ko = 0; ko < 64; ko += 32) {
            bf16x8 af[2], bfr[2];
            int pg = ((quad + (ko >> 3)) ^ (l16 & 7)) << 3;
            #pragma unroll
            for (int f = 0; f < 2; f++)
                af[f] = *(const bf16x8*)&sV[(wm * 32 + f * 16 + l16) * 64 + pg];
            #pragma unroll
            for (int f = 0; f < 2; f++)
                bfr[f] = *(const bf16x8*)&sK[(wn * 32 + f * 16 + l16) * 64 + pg];
            #pragma unroll
            for (int i = 0; i < 2; i++)
                #pragma unroll
                for (int j = 0; j < 2; j++)
                    acc[i][j] = __builtin_amdgcn_mfma_f32_16x16x32_bf16(af[i], bfr[j], acc[i][j], 0, 0, 0);
        }
        __syncthreads();
    }
    // write fp32 partial: kvp[sc][bh][m*64+d]
    float* kvout = kvp + ((size_t)sc * 64 + bh) * 4096;
    #pragma unroll
    for (int i = 0; i < 2; i++)
        #pragma unroll
        for (int j = 0; j < 2; j++)
            #pragma unroll
            for (int r = 0; r < 4; r++) {
                int m = wm * 32 + i * 16 + quad * 4 + r;
                int d = wn * 32 + j * 16 + l16;
                kvout[m * 64 + d] = acc[i][j][r];
            }
}

// ---------------- mid: kv partial reduce -> bf16 -----------------------------
// grid: 256 blocks = bh(64) x part(4); thread reduces one float4 over 8 sc.
__global__ __launch_bounds__(256) void mid_kernel(
        const float* __restrict__ kvp, unsigned short* __restrict__ kvb) {
    int bh = blockIdx.x >> 2, part = blockIdx.x & 3;
    int tid = threadIdx.x;
    int idx = (part * 256 + tid) * 4;
    float s0 = 0.f, s1 = 0.f, s2 = 0.f, s3 = 0.f;
    #pragma unroll
    for (int sc = 0; sc < 8; sc++) {
        float4 v = *(const float4*)&kvp[((size_t)sc * 64 + bh) * 4096 + idx];
        s0 += v.x; s1 += v.y; s2 += v.z; s3 += v.w;
    }
    ushort4 o; o.x = f2b(s0); o.y = f2b(s1); o.z = f2b(s2); o.w = f2b(s3);
    *(ushort4*)&kvb[(size_t)bh * 4096 + idx] = o;
}

// ---------------- fused out1 + output GEMM -----------------------------------
// grid: 512 1-D, XCD-swizzled (2 np blocks of one mtile -> same XCD).
// Each block: 128 rows x 256 cols (2 ntiles); o1/z/sQ computed ONCE per block.
__global__ __launch_bounds__(256, 2) void fused_out_kernel(
        const unsigned short* __restrict__ qb,
        const unsigned short* __restrict__ kvb, const float* __restrict__ ksg,
        const unsigned short* __restrict__ wto, const float* __restrict__ bo,
        float* __restrict__ out) {
    int g = blockIdx.x;
    int xcd = g & 7, slot = g >> 3;            // slot 0..63
    int mtile = xcd * 32 + (slot >> 1);
    int np = slot & 1;                         // col half: np*256 .. np*256+255

    __shared__ __align__(16) unsigned short sQ[128 * 64];
    __shared__ __align__(16) unsigned short sWo[2][128 * 64];
    __shared__ __align__(16) unsigned short sKV[64 * 64];
    __shared__ __align__(16) unsigned short sO1[128 * 64];
    __shared__ float sKsum[512];
    __shared__ float sZ[128];
    const int tid  = threadIdx.x;
    const int wave = tid >> 6, lane = tid & 63;
    const int wm = wave >> 1, wn = wave & 1;
    const int quad = lane >> 4, l16 = lane & 15;
    const int mbase = mtile * 128, nbase = np * 256;
    const int b = mtile >> 5;
    const int rsub = lane >> 3;
    const int coff = (((lane & 7) ^ rsub) << 3);

    // stage fp32 ksum for this b (512 cols = 8 h x 64 d)
    sKsum[tid]       = ksg[b * 512 + tid];
    sKsum[tid + 256] = ksg[b * 512 + 256 + tid];

    f32x4 accm[2][4][4];
    #pragma unroll
    for (int n = 0; n < 2; n++)
        #pragma unroll
        for (int i = 0; i < 4; i++)
            #pragma unroll
            for (int j = 0; j < 4; j++) accm[n][i][j] = (f32x4){0.f, 0.f, 0.f, 0.f};

    for (int h = 0; h < 8; h++) {
        #pragma unroll
        for (int t = 0; t < 4; t++) {
            int r0 = t * 32 + wave * 8;
            load_lds16(&qb[(size_t)(mbase + r0 + rsub) * 512 + h * 64 + coff], &sQ[r0 * 64]);
            load_lds16(&wto[(size_t)(nbase + r0 + rsub) * 512 + h * 64 + coff], &sWo[0][r0 * 64]);
            load_lds16(&wto[(size_t)(nbase + 128 + r0 + rsub) * 512 + h * 64 + coff], &sWo[1][r0 * 64]);
        }
        #pragma unroll
        for (int t = 0; t < 2; t++) {
            int r0 = t * 32 + wave * 8;
            load_lds16(&kvb[(size_t)(b * 8 + h) * 4096 + (r0 + rsub) * 64 + coff], &sKV[r0 * 64]);
        }
        __syncthreads();
        // z = 1/(q_h . ksum_h + eps) per row, from swizzled sQ (fp32 accum).
        {
            int row = tid >> 1, half = tid & 1;
            const float* ksh = &sKsum[h * 64];
            float dsum = 0.f;
            #pragma unroll
            for (int g2 = 0; g2 < 4; g2++) {
                int G = half * 4 + g2;                       // global octet
                uint4 w = *(const uint4*)&sQ[row * 64 + ((G ^ (row & 7)) << 3)];
                const unsigned int* qp = (const unsigned int*)&w;
                #pragma unroll
                for (int u = 0; u < 4; u++) {
                    int c = G * 8 + u * 2;
                    dsum += __builtin_bit_cast(float, qp[u] << 16)        * ksh[c];
                    dsum += __builtin_bit_cast(float, qp[u] & 0xFFFF0000u) * ksh[c + 1];
                }
            }
            dsum += __shfl_xor(dsum, 1, 64);
            if (!half) sZ[row] = 1.f / (dsum + 1e-6f);
        }
        __syncthreads();
        // o1 = q_h @ kv_h^T  (wave computes 64 rows x 32 m-cols)
        f32x4 acco[4][2];
        #pragma unroll
        for (int f = 0; f < 4; f++)
            #pragma unroll
            for (int j = 0; j < 2; j++) acco[f][j] = (f32x4){0.f, 0.f, 0.f, 0.f};
        #pragma unroll
        for (int ko = 0; ko < 64; ko += 32) {
            bf16x8 af[4], bfr[2];
            int pg = ((quad + (ko >> 3)) ^ (l16 & 7)) << 3;
            #pragma unroll
            for (int f = 0; f < 4; f++)
                af[f] = *(const bf16x8*)&sQ[(wm * 64 + f * 16 + l16) * 64 + pg];
            #pragma unroll
            for (int j = 0; j < 2; j++)
                bfr[j] = *(const bf16x8*)&sKV[(wn * 32 + j * 16 + l16) * 64 + pg];
            #pragma unroll
            for (int f = 0; f < 4; f++)
                #pragma unroll
                for (int j = 0; j < 2; j++)
                    acco[f][j] = __builtin_amdgcn_mfma_f32_16x16x32_bf16(af[f], bfr[j], acco[f][j], 0, 0, 0);
        }
        // scale by z, write to sO1 (swizzled A-layout)
        #pragma unroll
        for (int f = 0; f < 4; f++)
            #pragma unroll
            for (int j = 0; j < 2; j++)
                #pragma unroll
                for (int r = 0; r < 4; r++) {
                    int row = wm * 64 + f * 16 + quad * 4 + r;
                    int col = wn * 32 + j * 16 + l16;
                    float v = acco[f][j][r] * sZ[row];
                    int grp = col >> 3;
                    sO1[row * 64 + ((grp ^ (row & 7)) << 3) + (col & 7)] = f2b(v);
                }
        __syncthreads();
        // accumulate o1_h @ Wo_h for both ntiles (af shared)
        #pragma unroll
        for (int ko = 0; ko < 64; ko += 32) {
            bf16x8 af[4], bfr0[4], bfr1[4];
            int pg = ((quad + (ko >> 3)) ^ (l16 & 7)) << 3;
            #pragma unroll
            for (int f = 0; f < 4; f++)
                af[f] = *(const bf16x8*)&sO1[(wm * 64 + f * 16 + l16) * 64 + pg];
            #pragma unroll
            for (int f = 0; f < 4; f++) {
                bfr0[f] = *(const bf16x8*)&sWo[0][(wn * 64 + f * 16 + l16) * 64 + pg];
                bfr1[f] = *(const bf16x8*)&sWo[1][(wn * 64 + f * 16 + l16) * 64 + pg];
            }
            #pragma unroll
            for (int i = 0; i < 4; i++)
                #pragma unroll
                for (int j = 0; j < 4; j++) {
                    accm[0][i][j] = __builtin_amdgcn_mfma_f32_16x16x32_bf16(af[i], bfr0[j], accm[0][i][j], 0, 0, 0);
                    accm[1][i][j] = __builtin_amdgcn_mfma_f32_16x16x32_bf16(af[i], bfr1[j], accm[1][i][j], 0, 0, 0);
                }
        }
        __syncthreads();
    }
    #pragma unroll
    for (int n = 0; n < 2; n++)
        #pragma unroll
        for (int i = 0; i < 4; i++)
            #pragma unroll
            for (int j = 0; j < 4; j++) {
                int gcol = nbase + n * 128 + wn * 64 + j * 16 + l16;
                float bv = bo[gcol];
                #pragma unroll
                for (int r = 0; r < 4; r++) {
                    int grow = mbase + wm * 64 + i * 16 + quad * 4 + r;
                    out[(size_t)grow * 512 + gcol] = accm[n][i][j][r] + bv;
                }
            }
}

// ---------------- launch -----------------------------------------------------
extern "C" void kernel_launch(void* const* d_in, const int* in_sizes, int n_in,
                              void* d_out, int out_size, void* d_ws, size_t ws_size,
                              hipStream_t stream) {
    const float* x  = (const float*)d_in[0];
    const float* Wq = (const float*)d_in[1];
    const float* bq = (const float*)d_in[2];
    const float* Wk = (const float*)d_in[3];
    const float* bk = (const float*)d_in[4];
    const float* Wv = (const float*)d_in[5];
    const float* bv = (const float*)d_in[6];
    const float* Wo = (const float*)d_in[7];
    const float* bo = (const float*)d_in[8];
    float* out = (float*)d_out;

    char* wsb = (char*)d_ws;
    char* ob  = (char*)d_out;
    // d_out scratch (dead before fused_out writes):
    unsigned short* vT  = (unsigned short*)ob;                    // 32 MB
    unsigned short* xb  = (unsigned short*)(ob + 33554432ull);    // 32 MB, dead after gemm_qkv
    float*          kvp = (float*)(ob + 33554432ull);             // 8.4 MB, overlays xb
    // ws:
    unsigned short* qb  = (unsigned short*)wsb;                   // 32 MB
    unsigned short* kT  = (unsigned short*)(wsb + 33554432ull);   // 32 MB
    unsigned short* wt  = (unsigned short*)(wsb + 67108864ull);   // 2 MB
    unsigned short* kvb = (unsigned short*)(wsb + 69206016ull);   // 512 KB
    float*          ksg = (float*)(wsb + 69730304ull);            // 16 KB

    prep_kernel<<<16640, 256, 0, stream>>>(x, Wq, Wk, Wv, Wo, xb, wt, ksg);
    gemm_qkv_kernel<<<3072, 256, 0, stream>>>(xb, wt, bq, bk, bv, qb, kT, vT, ksg);
    kv_kernel<<<512, 256, 0, stream>>>(kT, vT, kvp);
    mid_kernel<<<256, 256, 0, stream>>>(kvp, kvb);
    fused_out_kernel<<<512, 256, 0, stream>>>(qb, kvb, ksg,
            wt + 3ull * 512 * 512, bo, out);
}